// Round 4
// baseline (175.819 us; speedup 1.0000x reference)
//
#include <hip/hip_runtime.h>

// Problem: y[b,c,0,h,w] = x[b,c,0,h,w]
//          y[b,c,n,h,w] = 0.3*x[b,c,n,h,w] + 0.7*y[b,c,n-1,h,w]
// Shapes: x,y = [4, 3, 32, 256, 256] fp32. Recurrence along axis 2 (N=32).
//
// v4 (resubmit after R3 infra failure -- container died twice, no kernel verdict).
// Copy-shaped issue. v2/v3 (one-shot blocks, LDS+barrier closure) were
// stuck at ~55 us vs the ~32 us traffic floor; occupancy/VGPR/NT-store knobs
// were all neutral, so the remaining suspect is issue shape: one-shot blocks
// whose 4 waves all stall at __syncthreads (vmcnt(0) drain for the LDS
// publish) and then die. The 6.3 TB/s copy kernel has persistent waves that
// never stop issuing loads.
//   - Segments -> LANES: wave = 16 chains x 4 segs. Carry closure by 12
//     __shfl, no LDS, no barrier. Waves fully independent.
//   - Persistent: 1024 blocks; each wave processes ITERS=3 items at constant
//     stride DELTA (+4 bc planes), software-pipelined: next item's 8 loads
//     are issued before the current item's shuffle+store phase, so each wave
//     holds ~8 loads in flight continuously.
// Bounds audit: q in [0,65536) covers bc 0..3; +DELTA -> 4..7; +2*DELTA -> 8..11.
// Max index = 6,291,455 = 12*32*16384-1 (last element). Full coverage, no OOB.
// Closure math identical to v2/v3 (absmax 0.0078125):
//   carry(s) = e[s-1] + 0.7^8 * e[s-2] + 0.7^16 * e[s-3],  y[n] = p[n] + 0.7^(n+1)*carry

typedef float vf4 __attribute__((ext_vector_type(4)));

constexpr int   NFR = 32;
constexpr int   HW4 = (256 * 256) / 4;  // 16384 float4 per frame-plane
constexpr int   FPS = 8;                // frames per segment
constexpr float WF  = 0.3f;
constexpr float OMW = 0.7f;

constexpr float P1  = 0.7f;
constexpr float P2  = P1 * 0.7f;
constexpr float P3  = P2 * 0.7f;
constexpr float P4  = P3 * 0.7f;
constexpr float P5  = P4 * 0.7f;
constexpr float P6  = P5 * 0.7f;
constexpr float P7  = P6 * 0.7f;
constexpr float P8  = P7 * 0.7f;
constexpr float P16 = P8 * P8;

constexpr int DELTA = 4 * NFR * HW4;     // item stride: +4 bc planes (2^21 float4)

static __device__ __forceinline__ vf4 shfl4(vf4 v, int src) {
    vf4 r;
    r.x = __shfl(v.x, src);
    r.y = __shfl(v.y, src);
    r.z = __shfl(v.z, src);
    r.w = __shfl(v.w, src);
    return r;
}

#define LOADS(p, B)              \
    p##0 = x[(B) + 0 * HW4];     \
    p##1 = x[(B) + 1 * HW4];     \
    p##2 = x[(B) + 2 * HW4];     \
    p##3 = x[(B) + 3 * HW4];     \
    p##4 = x[(B) + 4 * HW4];     \
    p##5 = x[(B) + 5 * HW4];     \
    p##6 = x[(B) + 6 * HW4];     \
    p##7 = x[(B) + 7 * HW4];

// local zero-IC prefix (seg 0 keeps true IC y[0] = x[0])
#define PREFIX(p)                       \
    p##0 = s0 ? p##0 : WF * p##0;       \
    p##1 = WF * p##1 + OMW * p##0;      \
    p##2 = WF * p##2 + OMW * p##1;      \
    p##3 = WF * p##3 + OMW * p##2;      \
    p##4 = WF * p##4 + OMW * p##3;      \
    p##5 = WF * p##5 + OMW * p##4;      \
    p##6 = WF * p##6 + OMW * p##5;      \
    p##7 = WF * p##7 + OMW * p##6;

// shuffle closure + corrected stores
#define CLOSE(p, B)                                                        \
    {                                                                      \
        const vf4 e0 = shfl4(p##7, c);                                     \
        const vf4 e1 = shfl4(p##7, c + 16);                                \
        const vf4 e2 = shfl4(p##7, c + 32);                                \
        vf4 carry = (vf4)(0.0f);                                           \
        if (seg == 1)      carry = e0;                                     \
        else if (seg == 2) carry = e1 + P8 * e0;                           \
        else if (seg == 3) carry = (e2 + P8 * e1) + P16 * e0;              \
        vf4 o;                                                             \
        o = p##0 + P1 * carry; __builtin_nontemporal_store(o, &y[(B) + 0 * HW4]); \
        o = p##1 + P2 * carry; __builtin_nontemporal_store(o, &y[(B) + 1 * HW4]); \
        o = p##2 + P3 * carry; __builtin_nontemporal_store(o, &y[(B) + 2 * HW4]); \
        o = p##3 + P4 * carry; __builtin_nontemporal_store(o, &y[(B) + 3 * HW4]); \
        o = p##4 + P5 * carry; __builtin_nontemporal_store(o, &y[(B) + 4 * HW4]); \
        o = p##5 + P6 * carry; __builtin_nontemporal_store(o, &y[(B) + 5 * HW4]); \
        o = p##6 + P7 * carry; __builtin_nontemporal_store(o, &y[(B) + 6 * HW4]); \
        o = p##7 + P8 * carry; __builtin_nontemporal_store(o, &y[(B) + 7 * HW4]); \
    }

__global__ __launch_bounds__(256, 4) void recfilt_kernel(const vf4* __restrict__ x,
                                                         vf4* __restrict__ y) {
    const int tid  = threadIdx.x;
    const int wv   = (blockIdx.x << 2) + (tid >> 6);  // global wave id [0, 4096)
    const int lane = tid & 63;
    const int c    = lane & 15;                       // chain slot within wave
    const int seg  = lane >> 4;                       // 0..3
    const bool s0  = (seg == 0);

    // item 0: chains q = 16*wv + c  ->  bc = q>>14, hw = q&16383
    const int q    = (wv << 4) + c;
    const int bc   = q >> 14;
    const int hw   = q & (HW4 - 1);
    const int base = bc * (NFR * HW4) + seg * (FPS * HW4) + hw;  // max idx 6.29M, int32 ok

    vf4 a0, a1, a2, a3, a4, a5, a6, a7;
    vf4 b0, b1, b2, b3, b4, b5, b6, b7;

    // software pipeline: issue item k+1's loads before item k's close/store
    LOADS(a, base)
    PREFIX(a)
    LOADS(b, base + DELTA)
    CLOSE(a, base)
    PREFIX(b)
    LOADS(a, base + 2 * DELTA)
    CLOSE(b, base + DELTA)
    PREFIX(a)
    CLOSE(a, base + 2 * DELTA)
}

extern "C" void kernel_launch(void* const* d_in, const int* in_sizes, int n_in,
                              void* d_out, int out_size, void* d_ws, size_t ws_size,
                              hipStream_t stream) {
    const vf4* x = (const vf4*)d_in[0];
    vf4*       y = (vf4*)d_out;
    // 196,608 chains x 4 segs = 786,432 items; 1024 blocks x 256 thr x 3 items
    recfilt_kernel<<<1024, 256, 0, stream>>>(x, y);
}

// Round 5
// 167.566 us; speedup vs baseline: 1.0493x; 1.0493x over previous
//
#include <hip/hip_runtime.h>

// Problem: y[b,c,0,h,w] = x[b,c,0,h,w]
//          y[b,c,n,h,w] = 0.3*x[b,c,n,h,w] + 0.7*y[b,c,n-1,h,w]
// Shapes: x,y = [4, 3, 32, 256, 256] fp32. Recurrence along axis 2 (N=32).
//
// v5: nontemporal on BOTH loads and stores.
// Evidence: v1 (seq), v2 (LDS closure), v3 (+launch_bounds/NT-store), v4
// (shuffle closure, persistent, pipelined) are ALL ~60 us. Occupancy, ILP,
// barriers, coalescing shape: falsified. Remaining theory: FETCH/WRITE_SIZE
// are TCC<->fabric, not DRAM. The harness's 402 MB poison fill leaves the
// 256 MB memory-side MALL full of DIRTY lines; our kernel's ~200 MB of new
// allocations (x reads + y writes) evict ~200 MB of poison -> hidden DRAM
// writebacks during our 60 us. Real DRAM traffic ~300+ MB = near-saturated.
// Fix attempt: nt loads + nt stores = no-allocate -> no eviction tax.
// Structure = v2/v3: 4 segs x 8 frames, LDS carry closure (one barrier),
// 3072 one-shot blocks, 32-bit indexing. Numerics unchanged (absmax 0.0078125).

typedef float vf4 __attribute__((ext_vector_type(4)));

constexpr int   NFR = 32;               // frames
constexpr int   HW4 = (256 * 256) / 4;  // float4 per frame-plane (16384 = 2^14)
constexpr int   FPS = 8;                // frames per segment
constexpr int   CPB = 64;               // chains per block
constexpr float WF  = 0.3f;
constexpr float OMW = 0.7f;

constexpr float P1  = 0.7f;
constexpr float P2  = P1 * 0.7f;
constexpr float P3  = P2 * 0.7f;
constexpr float P4  = P3 * 0.7f;
constexpr float P5  = P4 * 0.7f;
constexpr float P6  = P5 * 0.7f;
constexpr float P7  = P6 * 0.7f;
constexpr float P8  = P7 * 0.7f;
constexpr float P16 = P8 * P8;

__global__ __launch_bounds__(256, 8) void recfilt_kernel(const vf4* __restrict__ x,
                                                         vf4* __restrict__ y) {
    const int tid = threadIdx.x;
    const int c   = tid & (CPB - 1);   // chain slot within block
    const int seg = tid >> 6;          // 0..3, wave-uniform
    const int q   = blockIdx.x * CPB + c;      // global chain id [0, 196608)
    const int bc  = q >> 14;                   // q / HW4
    const int hw  = q & (HW4 - 1);             // q % HW4
    const int base = bc * (NFR * HW4) + seg * (FPS * HW4) + hw;   // int32 ok (max 6.29M)

    // ---- 8 independent nontemporal frame loads up front ----
    vf4 v0 = __builtin_nontemporal_load(&x[base + 0 * HW4]);
    vf4 v1 = __builtin_nontemporal_load(&x[base + 1 * HW4]);
    vf4 v2 = __builtin_nontemporal_load(&x[base + 2 * HW4]);
    vf4 v3 = __builtin_nontemporal_load(&x[base + 3 * HW4]);
    vf4 v4 = __builtin_nontemporal_load(&x[base + 4 * HW4]);
    vf4 v5 = __builtin_nontemporal_load(&x[base + 5 * HW4]);
    vf4 v6 = __builtin_nontemporal_load(&x[base + 6 * HW4]);
    vf4 v7 = __builtin_nontemporal_load(&x[base + 7 * HW4]);

    // ---- local prefix. seg 0 frame 0: y[0]=x[0] (leave v0). seg>0: zero IC ----
    if (seg != 0) v0 *= WF;
    v1 = WF * v1 + OMW * v0;
    v2 = WF * v2 + OMW * v1;
    v3 = WF * v3 + OMW * v2;
    v4 = WF * v4 + OMW * v3;
    v5 = WF * v5 + OMW * v4;
    v6 = WF * v6 + OMW * v5;
    v7 = WF * v7 + OMW * v6;

    // ---- publish segment-end partials, close the carry chain ----
    __shared__ vf4 lend[3][CPB];
    if (seg < 3) lend[seg][c] = v7;
    __syncthreads();

    vf4 carry = (vf4)(0.0f);
    if (seg == 1) {
        carry = lend[0][c];
    } else if (seg == 2) {
        carry = lend[1][c] + P8 * lend[0][c];
    } else if (seg == 3) {
        carry = (lend[2][c] + P8 * lend[1][c]) + P16 * lend[0][c];
    }

    // ---- y[n] = p[n] + 0.7^(n+1) * carry ; nontemporal stores ----
    vf4 o0 = v0 + P1 * carry;  __builtin_nontemporal_store(o0, &y[base + 0 * HW4]);
    vf4 o1 = v1 + P2 * carry;  __builtin_nontemporal_store(o1, &y[base + 1 * HW4]);
    vf4 o2 = v2 + P3 * carry;  __builtin_nontemporal_store(o2, &y[base + 2 * HW4]);
    vf4 o3 = v3 + P4 * carry;  __builtin_nontemporal_store(o3, &y[base + 3 * HW4]);
    vf4 o4 = v4 + P5 * carry;  __builtin_nontemporal_store(o4, &y[base + 4 * HW4]);
    vf4 o5 = v5 + P6 * carry;  __builtin_nontemporal_store(o5, &y[base + 5 * HW4]);
    vf4 o6 = v6 + P7 * carry;  __builtin_nontemporal_store(o6, &y[base + 6 * HW4]);
    vf4 o7 = v7 + P8 * carry;  __builtin_nontemporal_store(o7, &y[base + 7 * HW4]);
}

extern "C" void kernel_launch(void* const* d_in, const int* in_sizes, int n_in,
                              void* d_out, int out_size, void* d_ws, size_t ws_size,
                              hipStream_t stream) {
    const vf4* x = (const vf4*)d_in[0];
    vf4*       y = (vf4*)d_out;
    const int chains = 12 * HW4;                 // 196,608
    const int grid   = chains / CPB;             // 3072 blocks, 256 thr each
    recfilt_kernel<<<grid, 256, 0, stream>>>(x, y);
}